// Round 1
// baseline (138.388 us; speedup 1.0000x reference)
//
#include <hip/hip_runtime.h>
#include <math.h>

// TopoBrainPhysical: fused encoder MLP -> bilinear grid scatter -> ring-adjacency
// mixing -> node MLP -> readout MLP. One thread per batch element; everything
// fully unrolled (static register indexing); weights read via uniform global
// loads (scalar-cache friendly). fp32 throughout.

#define PI_F 3.14159265358979323846f

__device__ __forceinline__ float fast_tanh(float v) {
    // (e^{2x}-1)/(e^{2x}+1) with native exp2-based __expf and v_rcp.
    // Clamp so e never overflows; |err| ~1e-6, threshold is 6e-3.
    v = fminf(fmaxf(v, -15.0f), 15.0f);
    float e = __expf(2.0f * v);
    return (e - 1.0f) * __builtin_amdgcn_rcpf(e + 1.0f);
}

extern "C" __global__ void __launch_bounds__(256)
topo_fwd_kernel(const float* __restrict__ x,
                const float* __restrict__ ew1, const float* __restrict__ eb1,
                const float* __restrict__ ew2, const float* __restrict__ eb2,
                const float* __restrict__ ew3, const float* __restrict__ eb3,
                const float* __restrict__ nw1, const float* __restrict__ nb1,
                const float* __restrict__ nw2, const float* __restrict__ nb2,
                const float* __restrict__ alog, const float* __restrict__ rlog,
                const float* __restrict__ rw1, const float* __restrict__ rb1,
                const float* __restrict__ rw2, const float* __restrict__ rb2,
                float* __restrict__ out, int B)
{
    const int b = blockIdx.x * blockDim.x + threadIdx.x;
    if (b >= B) return;

    // ---------------- normalized adjacency (uniform values) ----------------
    // ang = softmax(alog)[None,:]*ANG_ADJ, row-normalized. A=4 ring: nbrs i±1.
    float ang[4][4];
    {
        float m = fmaxf(fmaxf(alog[0], alog[1]), fmaxf(alog[2], alog[3]));
        float e0 = __expf(alog[0] - m), e1 = __expf(alog[1] - m);
        float e2 = __expf(alog[2] - m), e3 = __expf(alog[3] - m);
        float s = e0 + e1 + e2 + e3;
        float sm[4] = { e0 / s, e1 / s, e2 / s, e3 / s };
        #pragma unroll
        for (int i = 0; i < 4; ++i) {
            const int jn = (i + 3) & 3, jp = (i + 1) & 3;
            float inv = 1.0f / fmaxf(sm[jn] + sm[jp], 1e-6f);
            #pragma unroll
            for (int j = 0; j < 4; ++j) {
                float adj = (j == jn || j == jp) ? 1.0f : 0.0f;
                ang[i][j] = sm[j] * adj * inv;
            }
        }
    }
    // rad: R=2 ring has adj=[[0,1],[1,0]]; row-normalization -> permutation,
    // but compute generally from rlog for faithfulness.
    float rad[2][2];
    {
        float m = fmaxf(rlog[0], rlog[1]);
        float f0 = __expf(rlog[0] - m), f1 = __expf(rlog[1] - m);
        float fs = f0 + f1;
        float sm0 = f0 / fs, sm1 = f1 / fs;
        rad[0][0] = 0.0f; rad[0][1] = sm1 / fmaxf(sm1, 1e-6f);
        rad[1][1] = 0.0f; rad[1][0] = sm0 / fmaxf(sm0, 1e-6f);
    }

    // ---------------- encoder (last timestep only) ----------------
    const float4 xv = *reinterpret_cast<const float4*>(x + (size_t)b * 60 + 56);

    float zt[24];
    #pragma unroll
    for (int j = 0; j < 24; ++j) {
        float a = eb1[j];
        a += xv.x * ew1[j];
        a += xv.y * ew1[24 + j];
        a += xv.z * ew1[48 + j];
        a += xv.w * ew1[72 + j];
        zt[j] = fast_tanh(a);
    }
    float zt2[24];
    #pragma unroll
    for (int j = 0; j < 24; ++j) {
        float a = eb2[j];
        #pragma unroll
        for (int k = 0; k < 24; ++k) a += zt[k] * ew2[k * 24 + j];
        zt2[j] = fast_tanh(a);
    }
    float z0 = eb3[0], z1 = eb3[1], z2 = eb3[2];
    #pragma unroll
    for (int k = 0; k < 24; ++k) {
        z0 += zt2[k] * ew3[k * 3 + 0];
        z1 += zt2[k] * ew3[k * 3 + 1];
        z2 += zt2[k] * ew3[k * 3 + 2];
    }

    // ---------------- bilinear corner weights ----------------
    const float r = 1.0f / (1.0f + __expf(-z0));      // * (R-1)=1
    const float p = (z1 + PI_F) / (2.0f * PI_F) * 4.0f;
    const float r0f = truncf(r), p0f = truncf(p);
    const float dr = r - r0f, dp = p - p0f;
    const int r0i = (int)r0f, p0i = (int)p0f;

    const float w0 = (1.0f - dr) * (1.0f - dp);
    const float w1c = (1.0f - dr) * dp;
    const float w2c = dr * (1.0f - dp);
    const float w3c = dr * dp;

    const int ri0 = min(r0i, 1);
    const int ri2 = min(r0i + 1, 1);
    const int pi0 = p0i & 3;          // floored mod 4 (works for negatives)
    const int pi1 = (p0i + 1) & 3;

    const int c0 = ri0 * 4 + pi0, c1 = ri0 * 4 + pi1;
    const int c2 = ri2 * 4 + pi0, c3 = ri2 * 4 + pi1;

    // grid cell n holds [z*cnt[n], wsum[n], 0...]; gather form (static idx).
    float cnt[8], wsum[8];
    #pragma unroll
    for (int n = 0; n < 8; ++n) {
        float cm = 0.0f, cw = 0.0f;
        if (c0 == n && w0 > 0.0f)  { cm += 1.0f; cw += w0; }
        if (c1 == n && w1c > 0.0f) { cm += 1.0f; cw += w1c; }
        if (c2 == n && w2c > 0.0f) { cm += 1.0f; cw += w2c; }
        if (c3 == n && w3c > 0.0f) { cm += 1.0f; cw += w3c; }
        cnt[n] = cm; wsum[n] = cw;
    }

    // ---------------- h + h_ang + h_rad (faithful .view() mixing) ----------
    // h_ang[n][e] = sum_j ang[n>>1][j] * h[2j+(n&1)][e]
    // h_rad[n][e] = sum_j rad[n>>2][j] * h[4j+(n&3)][e]
    // e<3 rows share factor z_e -> mix the 2 channels (cnt, wsum) only.
    float mc[8], mw[8];
    #pragma unroll
    for (int n = 0; n < 8; ++n) {
        float ac = cnt[n], aw = wsum[n];
        #pragma unroll
        for (int j = 0; j < 4; ++j) {
            const float g = ang[n >> 1][j];
            ac += g * cnt[2 * j + (n & 1)];
            aw += g * wsum[2 * j + (n & 1)];
        }
        #pragma unroll
        for (int j = 0; j < 2; ++j) {
            const float g = rad[n >> 2][j];
            ac += g * cnt[4 * j + (n & 3)];
            aw += g * wsum[4 * j + (n & 3)];
        }
        mc[n] = ac; mw[n] = aw;
    }

    // q[j] = z . nw1[0:3][j]  (shared across cells)
    float q[24];
    #pragma unroll
    for (int j = 0; j < 24; ++j)
        q[j] = z0 * nw1[j] + z1 * nw1[24 + j] + z2 * nw1[48 + j];

    // ---------------- node MLP + readout layer-1 accumulation --------------
    float t[24];
    #pragma unroll
    for (int j = 0; j < 24; ++j) t[j] = rb1[j];

    #pragma unroll
    for (int n = 0; n < 8; ++n) {
        float hid[24];
        #pragma unroll
        for (int j = 0; j < 24; ++j)
            hid[j] = fast_tanh(nb1[j] + mc[n] * q[j] + mw[n] * nw1[72 + j]);
        #pragma unroll
        for (int d = 0; d < 12; ++d) {
            float ho = nb2[d];
            #pragma unroll
            for (int j = 0; j < 24; ++j) ho += hid[j] * nw2[j * 12 + d];
            const int rbase = (n * 12 + d) * 24;
            #pragma unroll
            for (int j2 = 0; j2 < 24; ++j2) t[j2] += ho * rw1[rbase + j2];
        }
    }

    // ---------------- readout layer 2 ----------------
    float o0 = rb2[0], o1 = rb2[1], o2 = rb2[2], o3 = rb2[3];
    #pragma unroll
    for (int j = 0; j < 24; ++j) {
        const float tt = fast_tanh(t[j]);
        o0 += tt * rw2[j * 4 + 0];
        o1 += tt * rw2[j * 4 + 1];
        o2 += tt * rw2[j * 4 + 2];
        o3 += tt * rw2[j * 4 + 3];
    }
    float4 ov; ov.x = o0; ov.y = o1; ov.z = o2; ov.w = o3;
    *reinterpret_cast<float4*>(out + (size_t)b * 4) = ov;
}

extern "C" void kernel_launch(void* const* d_in, const int* in_sizes, int n_in,
                              void* d_out, int out_size, void* d_ws, size_t ws_size,
                              hipStream_t stream) {
    const float* x    = (const float*)d_in[0];
    const float* ew1  = (const float*)d_in[1];
    const float* eb1  = (const float*)d_in[2];
    const float* ew2  = (const float*)d_in[3];
    const float* eb2  = (const float*)d_in[4];
    const float* ew3  = (const float*)d_in[5];
    const float* eb3  = (const float*)d_in[6];
    const float* nw1  = (const float*)d_in[7];
    const float* nb1  = (const float*)d_in[8];
    const float* nw2  = (const float*)d_in[9];
    const float* nb2  = (const float*)d_in[10];
    const float* alog = (const float*)d_in[11];
    const float* rlog = (const float*)d_in[12];
    const float* rw1  = (const float*)d_in[13];
    const float* rb1  = (const float*)d_in[14];
    const float* rw2  = (const float*)d_in[15];
    const float* rb2  = (const float*)d_in[16];
    float* out = (float*)d_out;

    const int B = in_sizes[0] / 60;   // x is (B, 15, 4)
    const int block = 256;
    const int grid = (B + block - 1) / block;
    topo_fwd_kernel<<<grid, block, 0, stream>>>(
        x, ew1, eb1, ew2, eb2, ew3, eb3, nw1, nb1, nw2, nb2,
        alog, rlog, rw1, rb1, rw2, rb2, out, B);
}

// Round 2
// 99.898 us; speedup vs baseline: 1.3853x; 1.3853x over previous
//
#include <hip/hip_runtime.h>
#include <math.h>

// TopoBrainPhysical: fused encoder MLP -> bilinear grid scatter -> ring-adjacency
// mixing -> node MLP -> readout MLP. One thread per batch element; fully
// unrolled, static register indexing. launch_bounds(256,2): we only ever get
// 8 waves/CU (2048 waves total), so give the allocator the full 256-VGPR
// budget to avoid AGPR spill traffic (round-1: VGPR=76 < ~110 live => spills).

#define PI_F 3.14159265358979323846f

__device__ __forceinline__ float fast_tanh(float v) {
    // tanh(v) = 1 - 2/(e^{2v}+1). Saturates correctly: e->inf => 1, e->0 => -1.
    float e = __expf(2.0f * v);
    return 1.0f - 2.0f * __builtin_amdgcn_rcpf(e + 1.0f);
}

extern "C" __global__ void __launch_bounds__(256, 2)
topo_fwd_kernel(const float* __restrict__ x,
                const float* __restrict__ ew1, const float* __restrict__ eb1,
                const float* __restrict__ ew2, const float* __restrict__ eb2,
                const float* __restrict__ ew3, const float* __restrict__ eb3,
                const float* __restrict__ nw1, const float* __restrict__ nb1,
                const float* __restrict__ nw2, const float* __restrict__ nb2,
                const float* __restrict__ alog, const float* __restrict__ rlog,
                const float* __restrict__ rw1, const float* __restrict__ rb1,
                const float* __restrict__ rw2, const float* __restrict__ rb2,
                float* __restrict__ out, int B)
{
    const int b = blockIdx.x * blockDim.x + threadIdx.x;
    if (b >= B) return;

    // ---------------- normalized adjacency (wave-uniform) ----------------
    float ang[4][4];
    {
        float m = fmaxf(fmaxf(alog[0], alog[1]), fmaxf(alog[2], alog[3]));
        float e0 = __expf(alog[0] - m), e1 = __expf(alog[1] - m);
        float e2 = __expf(alog[2] - m), e3 = __expf(alog[3] - m);
        float s = e0 + e1 + e2 + e3;
        float sm[4] = { e0 / s, e1 / s, e2 / s, e3 / s };
        #pragma unroll
        for (int i = 0; i < 4; ++i) {
            const int jn = (i + 3) & 3, jp = (i + 1) & 3;
            float inv = 1.0f / fmaxf(sm[jn] + sm[jp], 1e-6f);
            #pragma unroll
            for (int j = 0; j < 4; ++j) {
                float adj = (j == jn || j == jp) ? 1.0f : 0.0f;
                ang[i][j] = sm[j] * adj * inv;
            }
        }
    }
    float rad[2][2];
    {
        float m = fmaxf(rlog[0], rlog[1]);
        float f0 = __expf(rlog[0] - m), f1 = __expf(rlog[1] - m);
        float fs = f0 + f1;
        float sm0 = f0 / fs, sm1 = f1 / fs;
        rad[0][0] = 0.0f; rad[0][1] = sm1 / fmaxf(sm1, 1e-6f);
        rad[1][1] = 0.0f; rad[1][0] = sm0 / fmaxf(sm0, 1e-6f);
    }

    // ---------------- encoder (last timestep only) ----------------
    const float4 xv = *reinterpret_cast<const float4*>(x + (size_t)b * 60 + 56);

    float zt[24];
    #pragma unroll
    for (int j = 0; j < 24; ++j) {
        float a = eb1[j];
        a += xv.x * ew1[j];
        a += xv.y * ew1[24 + j];
        a += xv.z * ew1[48 + j];
        a += xv.w * ew1[72 + j];
        zt[j] = fast_tanh(a);
    }
    float zt2[24];
    #pragma unroll
    for (int j = 0; j < 24; ++j) {
        float a = eb2[j];
        #pragma unroll
        for (int k = 0; k < 24; ++k) a += zt[k] * ew2[k * 24 + j];
        zt2[j] = fast_tanh(a);
    }
    float z0 = eb3[0], z1 = eb3[1], z2 = eb3[2];
    #pragma unroll
    for (int k = 0; k < 24; ++k) {
        z0 += zt2[k] * ew3[k * 3 + 0];
        z1 += zt2[k] * ew3[k * 3 + 1];
        z2 += zt2[k] * ew3[k * 3 + 2];
    }

    // ---------------- bilinear corner weights ----------------
    const float r = 1.0f / (1.0f + __expf(-z0));      // * (R-1)=1
    const float p = (z1 + PI_F) / (2.0f * PI_F) * 4.0f;
    const float r0f = truncf(r), p0f = truncf(p);
    const float dr = r - r0f, dp = p - p0f;
    const int r0i = (int)r0f, p0i = (int)p0f;

    const float w0 = (1.0f - dr) * (1.0f - dp);
    const float w1c = (1.0f - dr) * dp;
    const float w2c = dr * (1.0f - dp);
    const float w3c = dr * dp;

    const int ri0 = min(r0i, 1);
    const int ri2 = min(r0i + 1, 1);
    const int pi0 = p0i & 3;          // floored mod 4 (works for negatives)
    const int pi1 = (p0i + 1) & 3;

    const int c0 = ri0 * 4 + pi0, c1 = ri0 * 4 + pi1;
    const int c2 = ri2 * 4 + pi0, c3 = ri2 * 4 + pi1;

    // grid cell n holds [z*cnt[n], wsum[n], 0...]; gather form (static idx).
    float cnt[8], wsum[8];
    #pragma unroll
    for (int n = 0; n < 8; ++n) {
        float cm = 0.0f, cw = 0.0f;
        if (c0 == n && w0 > 0.0f)  { cm += 1.0f; cw += w0; }
        if (c1 == n && w1c > 0.0f) { cm += 1.0f; cw += w1c; }
        if (c2 == n && w2c > 0.0f) { cm += 1.0f; cw += w2c; }
        if (c3 == n && w3c > 0.0f) { cm += 1.0f; cw += w3c; }
        cnt[n] = cm; wsum[n] = cw;
    }

    // ---------------- h + h_ang + h_rad (faithful .view() mixing) ----------
    float mc[8], mw[8];
    #pragma unroll
    for (int n = 0; n < 8; ++n) {
        float ac = cnt[n], aw = wsum[n];
        #pragma unroll
        for (int j = 0; j < 4; ++j) {
            const float g = ang[n >> 1][j];
            ac += g * cnt[2 * j + (n & 1)];
            aw += g * wsum[2 * j + (n & 1)];
        }
        #pragma unroll
        for (int j = 0; j < 2; ++j) {
            const float g = rad[n >> 2][j];
            ac += g * cnt[4 * j + (n & 3)];
            aw += g * wsum[4 * j + (n & 3)];
        }
        mc[n] = ac; mw[n] = aw;
    }

    // q[j] = z . nw1[0:3][j]  (shared across cells)
    float q[24];
    #pragma unroll
    for (int j = 0; j < 24; ++j)
        q[j] = z0 * nw1[j] + z1 * nw1[24 + j] + z2 * nw1[48 + j];

    // ---------------- node MLP + readout layer-1 accumulation --------------
    float t[24];
    #pragma unroll
    for (int j = 0; j < 24; ++j) t[j] = rb1[j];

    #pragma unroll
    for (int n = 0; n < 8; ++n) {
        // incremental ho accumulation: no hid[24] array (live set -24 regs)
        float ho[12];
        #pragma unroll
        for (int d = 0; d < 12; ++d) ho[d] = nb2[d];
        #pragma unroll
        for (int j = 0; j < 24; ++j) {
            const float hj = fast_tanh(nb1[j] + mc[n] * q[j] + mw[n] * nw1[72 + j]);
            #pragma unroll
            for (int d = 0; d < 12; ++d) ho[d] += hj * nw2[j * 12 + d];
        }
        #pragma unroll
        for (int d = 0; d < 12; ++d) {
            const int rbase = (n * 12 + d) * 24;
            #pragma unroll
            for (int j2 = 0; j2 < 24; ++j2) t[j2] += ho[d] * rw1[rbase + j2];
        }
    }

    // ---------------- readout layer 2 ----------------
    float o0 = rb2[0], o1 = rb2[1], o2 = rb2[2], o3 = rb2[3];
    #pragma unroll
    for (int j = 0; j < 24; ++j) {
        const float tt = fast_tanh(t[j]);
        o0 += tt * rw2[j * 4 + 0];
        o1 += tt * rw2[j * 4 + 1];
        o2 += tt * rw2[j * 4 + 2];
        o3 += tt * rw2[j * 4 + 3];
    }
    float4 ov; ov.x = o0; ov.y = o1; ov.z = o2; ov.w = o3;
    *reinterpret_cast<float4*>(out + (size_t)b * 4) = ov;
}

extern "C" void kernel_launch(void* const* d_in, const int* in_sizes, int n_in,
                              void* d_out, int out_size, void* d_ws, size_t ws_size,
                              hipStream_t stream) {
    const float* x    = (const float*)d_in[0];
    const float* ew1  = (const float*)d_in[1];
    const float* eb1  = (const float*)d_in[2];
    const float* ew2  = (const float*)d_in[3];
    const float* eb2  = (const float*)d_in[4];
    const float* ew3  = (const float*)d_in[5];
    const float* eb3  = (const float*)d_in[6];
    const float* nw1  = (const float*)d_in[7];
    const float* nb1  = (const float*)d_in[8];
    const float* nw2  = (const float*)d_in[9];
    const float* nb2  = (const float*)d_in[10];
    const float* alog = (const float*)d_in[11];
    const float* rlog = (const float*)d_in[12];
    const float* rw1  = (const float*)d_in[13];
    const float* rb1  = (const float*)d_in[14];
    const float* rw2  = (const float*)d_in[15];
    const float* rb2  = (const float*)d_in[16];
    float* out = (float*)d_out;

    const int B = in_sizes[0] / 60;   // x is (B, 15, 4)
    const int block = 256;
    const int grid = (B + block - 1) / block;
    topo_fwd_kernel<<<grid, block, 0, stream>>>(
        x, ew1, eb1, ew2, eb2, ew3, eb3, nw1, nb1, nw2, nb2,
        alog, rlog, rw1, rb1, rw2, rb2, out, B);
}